// Round 3
// baseline (330.198 us; speedup 1.0000x reference)
//
#include <hip/hip_runtime.h>
#include <hip/hip_bf16.h>
#include <stdint.h>

// Problem constants (B,T,C) = (4,4096,1024)
#define TT 4096
#define BB 4
#define CC 1024
#define MM (BB * TT)          // 16384 rows
#define NCHUNK 128            // scan chunks along T
#define CHUNK_T (TT / NCHUNK) // 32 steps per chunk
#define NCHAIN (BB * CC)      // 4096 independent scan chains

typedef float f32x4 __attribute__((ext_vector_type(4)));
typedef __bf16 bf16x8 __attribute__((ext_vector_type(8)));

__device__ __forceinline__ float b2f(ushort u) {
  union { float f; uint32_t v; } x; x.v = ((uint32_t)u) << 16; return x.f;
}
__device__ __forceinline__ ushort f2b(float f) { // RNE fp32->bf16
  union { float f; uint32_t u; } x; x.f = f;
  uint32_t r = x.u + 0x7fffu + ((x.u >> 16) & 1u);
  return (ushort)(r >> 16);
}

// async global->LDS, 16B per lane. LDS dest must be uniform-base + lane*16.
__device__ __forceinline__ void async_copy16(const ushort* g, ushort* l) {
  __builtin_amdgcn_global_load_lds(
      (__attribute__((address_space(1))) void*)(g),
      (__attribute__((address_space(3))) void*)(l), 16, 0, 0);
}

// One kernel converts x, Wf, Wg, Wp to bf16. Sizes in float4 units:
// x: 4194304, each W: 262144. Total 4980736 = 19456 * 256 exactly.
__global__ __launch_bounds__(256) void cvt_all(const float* __restrict__ x,
                                               const float* __restrict__ wf,
                                               const float* __restrict__ wg,
                                               const float* __restrict__ wp,
                                               ushort* __restrict__ xb,
                                               ushort* __restrict__ wcat,
                                               ushort* __restrict__ wpb) {
  const int i = blockIdx.x * 256 + threadIdx.x;
  const float* s; ushort* d; int off;
  if (i < 4194304)            { s = x;  d = xb;              off = i; }
  else if (i < 4456448)       { s = wf; d = wcat;            off = i - 4194304; }
  else if (i < 4718592)       { s = wg; d = wcat + 1048576;  off = i - 4456448; }
  else                        { s = wp; d = wpb;             off = i - 4718592; }
  float4 v = ((const float4*)s)[off];
  ushort4 o;
  o.x = f2b(v.x); o.y = f2b(v.y); o.z = f2b(v.z); o.w = f2b(v.w);
  ((ushort4*)d)[off] = o;
}

// C[m][n] = sum_k A[m][k] * Bw[n][k]  (row-major, K=1024 contiguous).
// 128x128 tile, 4 waves 2x2, BK=32. OPERAND-SWAPPED MFMA: mfma(b_frag, a_frag)
// puts n on the reg axis (4 consecutive n per lane) -> 4-wide packed stores.
// MODE 0: f32x4 stores. MODE 1: sigmoid (n<1024) / tanh (n>=1024), ushort4 stores.
// LDS XOR swizzle (round-2 verified, conflicts=0): slot s of row r holds
// global k-chunk s ^ ((r>>1)&3).
template <int MODE>
__global__ __launch_bounds__(256) void gemm_bt(const ushort* __restrict__ A,
                                               const ushort* __restrict__ Bw,
                                               float* __restrict__ outF,
                                               ushort* __restrict__ outB, int N) {
  constexpr int K = CC;
  __shared__ __align__(16) ushort sA[128 * 32];
  __shared__ __align__(16) ushort sB[128 * 32];
  const int tid = threadIdx.x;
  const int lane = tid & 63;
  const int wid = tid >> 6;
  const int wm = wid >> 1, wn = wid & 1;
  const long m0 = (long)blockIdx.y * 128;
  const long n0 = (long)blockIdx.x * 128;

  f32x4 acc[4][4];
#pragma unroll
  for (int i = 0; i < 4; ++i)
#pragma unroll
    for (int j = 0; j < 4; ++j) acc[i][j] = (f32x4){0.f, 0.f, 0.f, 0.f};

  // staging fetch: lane -> row = lane>>2, k-chunk = (lane&3) ^ ((lane>>3)&3)
  const int srow = lane >> 2;
  const int kcf = (lane & 3) ^ ((lane >> 3) & 3);
  const ushort* Ab = A + (m0 + srow) * K + kcf * 8;
  const ushort* Bb = Bw + (n0 + srow) * K + kcf * 8;
  // fragment read slot for row r: (k-quad) ^ ((r>>1)&3); row bits from lane&15
  const int slot = (lane >> 4) ^ ((lane >> 1) & 3);
  const int rlo = lane & 15;

  for (int k0 = 0; k0 < K; k0 += 32) {
#pragma unroll
    for (int half = 0; half < 2; ++half) {
      const int ch = wid + half * 4; // chunks 0..7 (16 rows each)
      async_copy16(Ab + (long)ch * 16 * K + k0, &sA[ch * 512 + lane * 8]);
      async_copy16(Bb + (long)ch * 16 * K + k0, &sB[ch * 512 + lane * 8]);
    }
    __syncthreads();

    bf16x8 af[4], bfr[4];
#pragma unroll
    for (int i = 0; i < 4; ++i) {
      af[i]  = *(const bf16x8*)&sA[(wm * 64 + i * 16 + rlo) * 32 + slot * 8];
      bfr[i] = *(const bf16x8*)&sB[(wn * 64 + i * 16 + rlo) * 32 + slot * 8];
    }
#pragma unroll
    for (int i = 0; i < 4; ++i)
#pragma unroll
      for (int j = 0; j < 4; ++j)
        acc[i][j] = __builtin_amdgcn_mfma_f32_16x16x32_bf16(bfr[j], af[i], acc[i][j], 0, 0, 0);
    __syncthreads();
  }

  // Swapped C/D mapping: m = lane&15 axis, n = (lane>>4)*4 + reg axis.
  const int mloc = lane & 15;
  const int rq = lane >> 4;
#pragma unroll
  for (int i = 0; i < 4; ++i) {
    const long m = m0 + wm * 64 + i * 16 + mloc;
#pragma unroll
    for (int j = 0; j < 4; ++j) {
      const long nb = n0 + wn * 64 + j * 16 + rq * 4; // 4 consecutive n
      const f32x4 v = acc[i][j];
      if (MODE == 0) {
        *(f32x4*)(outF + m * N + nb) = v;
      } else {
        float act[4];
        if (n0 < CC) { // sigmoid region (uniform per block)
#pragma unroll
          for (int r = 0; r < 4; ++r)
            act[r] = __builtin_amdgcn_rcpf(1.f + __expf(-v[r]));
        } else {       // tanh = 1 - 2/(exp(2v)+1)
#pragma unroll
          for (int r = 0; r < 4; ++r)
            act[r] = fmaf(-2.f, __builtin_amdgcn_rcpf(1.f + __expf(2.f * v[r])), 1.f);
        }
        ushort4 o;
        o.x = f2b(act[0]); o.y = f2b(act[1]); o.z = f2b(act[2]); o.w = f2b(act[3]);
        *(ushort4*)(outB + m * (long)N + nb) = o;
      }
    }
  }
}

// P layout: [m=b*T+t][0..1023]=f (bf16), [1024..2047]=g (bf16)
// Recurrence h_t = f*h + (1-f)*g. Four chains per thread (ushort4 loads).
__global__ __launch_bounds__(256) void scan_pass1(const ushort* __restrict__ P,
                                                  float* __restrict__ cA,
                                                  float* __restrict__ cB) {
  const int pc = blockIdx.x * 256 + threadIdx.x; // chain quad 0..1023
  const int chunk = blockIdx.y;
  const int b = pc >> 8, c4 = (pc & 255) * 4;
  const ushort4* p =
      (const ushort4*)(P + (size_t)(b * TT + chunk * CHUNK_T) * (2 * CC) + c4);
  float A[4] = {1.f, 1.f, 1.f, 1.f};
  float h[4] = {0.f, 0.f, 0.f, 0.f};
#pragma unroll 4
  for (int i = 0; i < CHUNK_T; ++i) {
    const ushort4 fu = p[0];
    const ushort4 gu = p[CC / 4];
    p += 2 * CC / 4;
    const float f[4] = {b2f(fu.x), b2f(fu.y), b2f(fu.z), b2f(fu.w)};
    const float g[4] = {b2f(gu.x), b2f(gu.y), b2f(gu.z), b2f(gu.w)};
#pragma unroll
    for (int r = 0; r < 4; ++r) {
      A[r] *= f[r];
      h[r] = fmaf(f[r], h[r], (1.f - f[r]) * g[r]);
    }
  }
  const int ci = chunk * NCHAIN + b * CC + c4;
  *(f32x4*)(cA + ci) = (f32x4){A[0], A[1], A[2], A[3]};
  *(f32x4*)(cB + ci) = (f32x4){h[0], h[1], h[2], h[3]};
}

// Carry computed inline (scan over prior chunks' cA/cB), then fixup + write H.
__global__ __launch_bounds__(256) void scan_pass3(const ushort* __restrict__ P,
                                                  const float* __restrict__ cA,
                                                  const float* __restrict__ cB,
                                                  ushort* __restrict__ H) {
  const int pc = blockIdx.x * 256 + threadIdx.x;
  const int chunk = blockIdx.y;
  const int b = pc >> 8, c4 = (pc & 255) * 4;
  const int ci = b * CC + c4;
  float h[4] = {0.f, 0.f, 0.f, 0.f};
  for (int j = 0; j < chunk; ++j) {
    const f32x4 a = *(const f32x4*)(cA + j * NCHAIN + ci);
    const f32x4 bb = *(const f32x4*)(cB + j * NCHAIN + ci);
#pragma unroll
    for (int r = 0; r < 4; ++r) h[r] = fmaf(a[r], h[r], bb[r]);
  }
  const ushort4* p =
      (const ushort4*)(P + (size_t)(b * TT + chunk * CHUNK_T) * (2 * CC) + c4);
  ushort4* hp = (ushort4*)(H + (size_t)(b * TT + chunk * CHUNK_T) * CC + c4);
#pragma unroll 4
  for (int i = 0; i < CHUNK_T; ++i) {
    const ushort4 fu = p[0];
    const ushort4 gu = p[CC / 4];
    p += 2 * CC / 4;
    const float f[4] = {b2f(fu.x), b2f(fu.y), b2f(fu.z), b2f(fu.w)};
    const float g[4] = {b2f(gu.x), b2f(gu.y), b2f(gu.z), b2f(gu.w)};
    ushort4 o;
#pragma unroll
    for (int r = 0; r < 4; ++r)
      h[r] = fmaf(f[r], h[r], (1.f - f[r]) * g[r]);
    o.x = f2b(h[0]); o.y = f2b(h[1]); o.z = f2b(h[2]); o.w = f2b(h[3]);
    *hp = o;
    hp += CC / 4;
  }
}

extern "C" void kernel_launch(void* const* d_in, const int* in_sizes, int n_in,
                              void* d_out, int out_size, void* d_ws, size_t ws_size,
                              hipStream_t stream) {
  const float* x  = (const float*)d_in[0];
  const float* Wf = (const float*)d_in[1];
  const float* Wg = (const float*)d_in[2];
  const float* Wp = (const float*)d_in[3];

  // workspace layout (bytes); H aliases xb (xb dead after gates GEMM, stream-ordered)
  char* ws = (char*)d_ws;
  ushort* xb   = (ushort*)(ws);                                  // 33554432 B
  ushort* Hb   = xb;                                             // alias
  ushort* Wcat = (ushort*)(ws + 33554432);                       //  4194304 B (Wf||Wg)
  ushort* Wpb  = (ushort*)(ws + 33554432 + 4194304);             //  2097152 B
  ushort* P    = (ushort*)(ws + 33554432 + 4194304 + 2097152);   // 67108864 B (f||g bf16)
  char* tail   = ws + 33554432 + 4194304 + 2097152 + 67108864;
  float* cA    = (float*)(tail);                                 // 2 MiB (128*4096*4)
  float* cB    = (float*)(tail + 2097152);                       // 2 MiB
  (void)ws_size; (void)in_sizes; (void)n_in; (void)out_size;

  // 1) all fp32 -> bf16 conversions in one launch
  cvt_all<<<19456, 256, 0, stream>>>(x, Wf, Wg, Wp, xb, Wcat, Wpb);

  // 2) gates GEMM: [16384 x 2048] = xb @ Wcat^T, fused sigmoid/tanh -> P (bf16)
  dim3 g1(2 * CC / 128, MM / 128);
  gemm_bt<1><<<g1, 256, 0, stream>>>(xb, Wcat, nullptr, P, 2 * CC);

  // 3) chunked scan: pass1 per-chunk compose, pass3 inline-carry + fixup
  dim3 gs(NCHAIN / 4 / 256, NCHUNK);
  scan_pass1<<<gs, 256, 0, stream>>>(P, cA, cB);
  scan_pass3<<<gs, 256, 0, stream>>>(P, cA, cB, Hb);

  // 4) projection GEMM: out = H @ Wp^T (fp32), 128x128 tile
  dim3 g3(CC / 128, MM / 128);
  gemm_bt<0><<<g3, 256, 0, stream>>>(Hb, Wpb, (float*)d_out, nullptr, CC);
}